// Round 11
// baseline (83.051 us; speedup 1.0000x reference)
//
#include <hip/hip_runtime.h>

#define N_NODES 100000
#define N_EDGES 320000
#define Q 4096
#define HID 128
#define DIN 256
#define EMB_LD 260      // DIN + 4 pad: q-rows land on distinct bank groups
#define NSLOT (3 * Q)   // 12288
#define CAP 64
#define QPB 4

// ---------------- K1: slot = -1 ----------------
__global__ __launch_bounds__(256) void k_init(int4* __restrict__ slot4) {
    int i = blockIdx.x * 256 + threadIdx.x;
    if (i < N_NODES / 4) slot4[i] = make_int4(-1, -1, -1, -1);
}

// ---------------- K2: claim slots via CAS + zero cnt ----------------
__global__ __launch_bounds__(256) void k_claim(const int* __restrict__ s_idx,
                                               const int* __restrict__ p_idx,
                                               const int* __restrict__ n_idx,
                                               int* __restrict__ slot,
                                               int* __restrict__ cnt) {
    int i = blockIdx.x * 256 + threadIdx.x;   // 0 .. NSLOT-1
    cnt[i] = 0;
    int t = i >> 12;
    int q = i & (Q - 1);
    int node = (t == 0 ? s_idx : (t == 1 ? p_idx : n_idx))[q];
    atomicCAS(&slot[node], -1, i);
}

// ---------------- K3: build per-slot edge lists (int2 = {e, td}) -------
__global__ __launch_bounds__(256) void k_build(
    const int* __restrict__ src, const int* __restrict__ dst,
    const float* __restrict__ bt, const float* __restrict__ node_ts,
    const int* __restrict__ slot, int* __restrict__ cnt,
    int2* __restrict__ edata) {
    int e = blockIdx.x * 256 + threadIdx.x;
    if (e >= N_EDGES) return;
    int sl = slot[dst[e]];
    if (sl < 0) return;
    float td = bt[e] - node_ts[src[e]];
    int pos = atomicAdd(&cnt[sl], 1);
    if (pos < CAP) edata[sl * CAP + pos] = make_int2(e, __float_as_int(td));
}

// ---------------- K4: fused emb-build + predictor ----------------
// 1024 blocks x 256 threads (4 waves), 4 queries per block.
// Phase A: wave w owns rows {w, w+4, w+8}; j=lane>>4 edge slot, g=lane&15.
// Phase B: wave w owns cols [32w,32w+32); lane = (q=lane>>4, g2=lane&15).
__global__ __launch_bounds__(256) void k_fused(
    const int* __restrict__ s_idx, const int* __restrict__ p_idx,
    const int* __restrict__ n_idx, const int* __restrict__ slot,
    const int* __restrict__ cnt, const int2* __restrict__ edata,
    const float* __restrict__ ef,
    const float* __restrict__ time_w, const float* __restrict__ time_b,
    const float* __restrict__ W_src, const float* __restrict__ b_src,
    const float* __restrict__ W_dst, const float* __restrict__ b_dst,
    const float* __restrict__ W_out, const float* __restrict__ b_out,
    float* __restrict__ out) {
    __shared__ float emb[QPB * 3][EMB_LD];   // ~12.5 KB
    __shared__ float pP[QPB][4], pN[QPB][4];
    const int tid   = threadIdx.x;
    const int qbase = blockIdx.x * QPB;
    const int w     = tid >> 6;
    const int lane  = tid & 63;

    // ---- Phase A: lane-parallel gather (3 rows per wave) ----
    {
        const int j = lane >> 4;          // edge slot 0..3
        const int g = lane & 15;          // col group 0..15
        const float4 tw0 = *reinterpret_cast<const float4*>(time_w + 8 * g);
        const float4 tw1 = *reinterpret_cast<const float4*>(time_w + 8 * g + 4);
        const float4 tb0 = *reinterpret_cast<const float4*>(time_b + 8 * g);
        const float4 tb1 = *reinterpret_cast<const float4*>(time_b + 8 * g + 4);
        #pragma unroll
        for (int rr = 0; rr < 3; ++rr) {
            const int row = w + rr * 4;   // 0..11
            int t = row >> 2, q = row & 3;
            const int* ia = (t == 0) ? s_idx : (t == 1) ? p_idx : n_idx;
            int sl = slot[ia[qbase + q]];
            int n = cnt[sl]; if (n > CAP) n = CAP;
            float4 accA = {0.f, 0.f, 0.f, 0.f}, accB = {0.f, 0.f, 0.f, 0.f};
            float4 tcA  = {0.f, 0.f, 0.f, 0.f}, tcB  = {0.f, 0.f, 0.f, 0.f};
            for (int jb = j; jb < n; jb += 4) {
                int2 ed = edata[(size_t)sl * CAP + jb];
                const float* rp = ef + (size_t)ed.x * 128;
                float4 vA = *reinterpret_cast<const float4*>(rp + 4 * g);
                float4 vB = *reinterpret_cast<const float4*>(rp + 64 + 4 * g);
                float td = __int_as_float(ed.y);
                accA.x += vA.x; accA.y += vA.y; accA.z += vA.z; accA.w += vA.w;
                accB.x += vB.x; accB.y += vB.y; accB.z += vB.z; accB.w += vB.w;
                tcA.x += __cosf(td * tw0.x + tb0.x);
                tcA.y += __cosf(td * tw0.y + tb0.y);
                tcA.z += __cosf(td * tw0.z + tb0.z);
                tcA.w += __cosf(td * tw0.w + tb0.w);
                tcB.x += __cosf(td * tw1.x + tb1.x);
                tcB.y += __cosf(td * tw1.y + tb1.y);
                tcB.z += __cosf(td * tw1.z + tb1.z);
                tcB.w += __cosf(td * tw1.w + tb1.w);
            }
#define RED2(v) { v += __shfl_xor(v, 16); v += __shfl_xor(v, 32); }
            RED2(accA.x) RED2(accA.y) RED2(accA.z) RED2(accA.w)
            RED2(accB.x) RED2(accB.y) RED2(accB.z) RED2(accB.w)
            RED2(tcA.x)  RED2(tcA.y)  RED2(tcA.z)  RED2(tcA.w)
            RED2(tcB.x)  RED2(tcB.y)  RED2(tcB.z)  RED2(tcB.w)
#undef RED2
            if (j == 0) {
                *reinterpret_cast<float4*>(&emb[row][4 * g])       = accA;
                *reinterpret_cast<float4*>(&emb[row][64 + 4 * g])  = accB;
                *reinterpret_cast<float4*>(&emb[row][128 + 8 * g]) = tcA;
                *reinterpret_cast<float4*>(&emb[row][132 + 8 * g]) = tcB;
            }
        }
    }
    __syncthreads();

    // ---- Phase B: GEMM + relu + W_out dot ----
    {
        const int q       = lane >> 4;        // 0..3
        const int g2      = lane & 15;        // 0..15
        const int colbase = 32 * w + 2 * g2;  // wave covers 32 cols, 2/lane

        float2 bs = *reinterpret_cast<const float2*>(b_src + colbase);
        float2 bd = *reinterpret_cast<const float2*>(b_dst + colbase);
        float aS[2] = {bs.x, bs.y};
        float aP[2] = {bd.x, bd.y};
        float aN[2] = {bd.x, bd.y};

        const float* e_s = emb[q];
        const float* e_p = emb[QPB + q];
        const float* e_n = emb[2 * QPB + q];

        for (int k = 0; k < DIN; k += 4) {
            float4 sv = *reinterpret_cast<const float4*>(e_s + k);
            float4 pv = *reinterpret_cast<const float4*>(e_p + k);
            float4 nv = *reinterpret_cast<const float4*>(e_n + k);
            #pragma unroll
            for (int kk = 0; kk < 4; ++kk) {
                float2 ws = *reinterpret_cast<const float2*>(W_src + (size_t)(k + kk) * HID + colbase);
                float2 wd = *reinterpret_cast<const float2*>(W_dst + (size_t)(k + kk) * HID + colbase);
                float s1 = (&sv.x)[kk], p1 = (&pv.x)[kk], n1 = (&nv.x)[kk];
                aS[0] += s1 * ws.x;  aS[1] += s1 * ws.y;
                aP[0] += p1 * wd.x;  aP[1] += p1 * wd.y;
                aN[0] += n1 * wd.x;  aN[1] += n1 * wd.y;
            }
        }

        float2 wo = *reinterpret_cast<const float2*>(W_out + colbase);
        float rP = fmaxf(aS[0] + aP[0], 0.f) * wo.x + fmaxf(aS[1] + aP[1], 0.f) * wo.y;
        float rN = fmaxf(aS[0] + aN[0], 0.f) * wo.x + fmaxf(aS[1] + aN[1], 0.f) * wo.y;
        rP += __shfl_xor(rP, 1); rP += __shfl_xor(rP, 2);
        rP += __shfl_xor(rP, 4); rP += __shfl_xor(rP, 8);
        rN += __shfl_xor(rN, 1); rN += __shfl_xor(rN, 2);
        rN += __shfl_xor(rN, 4); rN += __shfl_xor(rN, 8);
        if (g2 == 0) { pP[q][w] = rP; pN[q][w] = rN; }
    }
    __syncthreads();

    if (tid < QPB) {
        float bo = b_out[0];
        out[qbase + tid]     = pP[tid][0] + pP[tid][1] + pP[tid][2] + pP[tid][3] + bo;
        out[Q + qbase + tid] = pN[tid][0] + pN[tid][1] + pN[tid][2] + pN[tid][3] + bo;
    }
}

// ---------------- launch ----------------

extern "C" void kernel_launch(void* const* d_in, const int* in_sizes, int n_in,
                              void* d_out, int out_size, void* d_ws, size_t ws_size,
                              hipStream_t stream) {
    const int*   src     = (const int*)d_in[0];
    const int*   dst     = (const int*)d_in[1];
    const float* ef      = (const float*)d_in[2];
    const float* bt      = (const float*)d_in[3];
    const float* node_ts = (const float*)d_in[4];
    const int*   s_idx   = (const int*)d_in[5];
    const int*   p_idx   = (const int*)d_in[6];
    const int*   n_idx   = (const int*)d_in[7];
    const float* time_w  = (const float*)d_in[8];
    const float* time_b  = (const float*)d_in[9];
    const float* W_src   = (const float*)d_in[10];
    const float* b_src   = (const float*)d_in[11];
    const float* W_dst   = (const float*)d_in[12];
    const float* b_dst   = (const float*)d_in[13];
    const float* W_out   = (const float*)d_in[14];
    const float* b_out   = (const float*)d_in[15];
    float*       out     = (float*)d_out;

    // workspace layout (bytes)
    char* ws = (char*)d_ws;
    int*   slot  = (int*)ws;                          // [100000]
    int*   cnt   = (int*)(ws + 512 * 1024);           // [12288]
    int2*  edata = (int2*)(ws + 1024 * 1024);         // [12288*64] int2 = 6.3 MB

    k_init<<<(N_NODES / 4 + 255) / 256, 256, 0, stream>>>((int4*)slot);
    k_claim<<<NSLOT / 256, 256, 0, stream>>>(s_idx, p_idx, n_idx, slot, cnt);
    k_build<<<(N_EDGES + 255) / 256, 256, 0, stream>>>(src, dst, bt, node_ts,
                                                       slot, cnt, edata);
    k_fused<<<Q / QPB, 256, 0, stream>>>(s_idx, p_idx, n_idx, slot, cnt,
                                         edata, ef, time_w, time_b,
                                         W_src, b_src, W_dst, b_dst,
                                         W_out, b_out, out);
}

// Round 13
// 60.709 us; speedup vs baseline: 1.3680x; 1.3680x over previous
//
#include <hip/hip_runtime.h>

#define N_NODES 100000
#define N_EDGES 320000
#define Q 4096
#define HID 128
#define DIN 256
#define NSLOT (3 * Q)   // 12288
#define CAP 64
#define QPB 16

// ---------------- K1: slot = -1, cnt = 0 ----------------
__global__ __launch_bounds__(256) void k_init(int4* __restrict__ slot4,
                                              int4* __restrict__ cnt4) {
    int i = blockIdx.x * 256 + threadIdx.x;
    if (i < N_NODES / 4) slot4[i] = make_int4(-1, -1, -1, -1);
    else if (i < N_NODES / 4 + NSLOT / 4) cnt4[i - N_NODES / 4] = make_int4(0, 0, 0, 0);
}

// ---------------- K2: claim slots via CAS ----------------
__global__ __launch_bounds__(256) void k_claim(const int* __restrict__ s_idx,
                                               const int* __restrict__ p_idx,
                                               const int* __restrict__ n_idx,
                                               int* __restrict__ slot) {
    int i = blockIdx.x * 256 + threadIdx.x;   // 0 .. NSLOT-1
    int t = i >> 12;
    int q = i & (Q - 1);
    int node = (t == 0 ? s_idx : (t == 1 ? p_idx : n_idx))[q];
    atomicCAS(&slot[node], -1, i);
}

// ---------------- K3: build per-slot edge lists (int2 = {e, td}) -------
__global__ __launch_bounds__(256) void k_build(
    const int* __restrict__ src, const int* __restrict__ dst,
    const float* __restrict__ bt, const float* __restrict__ node_ts,
    const int* __restrict__ slot, int* __restrict__ cnt,
    int2* __restrict__ edata) {
    int e = blockIdx.x * 256 + threadIdx.x;
    if (e >= N_EDGES) return;
    int sl = slot[dst[e]];
    if (sl < 0) return;
    float td = bt[e] - node_ts[src[e]];
    int pos = atomicAdd(&cnt[sl], 1);
    if (pos < CAP) edata[sl * CAP + pos] = make_int2(e, __float_as_int(td));
}

// ---------------- K4: aggregate h rows, one slot per wave --------------
// 3072 blocks x 256 threads = 12288 waves; lane-parallel over 4 edge slots.
__global__ __launch_bounds__(256) void k_aggregate(
    const int* __restrict__ cnt, const int2* __restrict__ edata,
    const float* __restrict__ ef,
    const float* __restrict__ time_w, const float* __restrict__ time_b,
    float* __restrict__ h) {
    const int s    = (blockIdx.x * 256 + threadIdx.x) >> 6;  // slot 0..12287
    const int lane = threadIdx.x & 63;
    const int j    = lane >> 4;       // edge slot 0..3
    const int g    = lane & 15;       // col group 0..15
    const float4 tw0 = *reinterpret_cast<const float4*>(time_w + 8 * g);
    const float4 tw1 = *reinterpret_cast<const float4*>(time_w + 8 * g + 4);
    const float4 tb0 = *reinterpret_cast<const float4*>(time_b + 8 * g);
    const float4 tb1 = *reinterpret_cast<const float4*>(time_b + 8 * g + 4);

    int n = cnt[s]; if (n > CAP) n = CAP;
    float4 accA = {0.f, 0.f, 0.f, 0.f}, accB = {0.f, 0.f, 0.f, 0.f};
    float4 tcA  = {0.f, 0.f, 0.f, 0.f}, tcB  = {0.f, 0.f, 0.f, 0.f};
    for (int jb = j; jb < n; jb += 4) {
        int2 ed = edata[(size_t)s * CAP + jb];
        const float* rp = ef + (size_t)ed.x * 128;
        float4 vA = *reinterpret_cast<const float4*>(rp + 4 * g);
        float4 vB = *reinterpret_cast<const float4*>(rp + 64 + 4 * g);
        float td = __int_as_float(ed.y);
        accA.x += vA.x; accA.y += vA.y; accA.z += vA.z; accA.w += vA.w;
        accB.x += vB.x; accB.y += vB.y; accB.z += vB.z; accB.w += vB.w;
        tcA.x += __cosf(td * tw0.x + tb0.x);
        tcA.y += __cosf(td * tw0.y + tb0.y);
        tcA.z += __cosf(td * tw0.z + tb0.z);
        tcA.w += __cosf(td * tw0.w + tb0.w);
        tcB.x += __cosf(td * tw1.x + tb1.x);
        tcB.y += __cosf(td * tw1.y + tb1.y);
        tcB.z += __cosf(td * tw1.z + tb1.z);
        tcB.w += __cosf(td * tw1.w + tb1.w);
    }
#define RED2(v) { v += __shfl_xor(v, 16); v += __shfl_xor(v, 32); }
    RED2(accA.x) RED2(accA.y) RED2(accA.z) RED2(accA.w)
    RED2(accB.x) RED2(accB.y) RED2(accB.z) RED2(accB.w)
    RED2(tcA.x)  RED2(tcA.y)  RED2(tcA.z)  RED2(tcA.w)
    RED2(tcB.x)  RED2(tcB.y)  RED2(tcB.z)  RED2(tcB.w)
#undef RED2
    if (j == 0) {
        float* hp = h + (size_t)s * DIN;
        *reinterpret_cast<float4*>(hp + 4 * g)       = accA;
        *reinterpret_cast<float4*>(hp + 64 + 4 * g)  = accB;
        *reinterpret_cast<float4*>(hp + 128 + 8 * g) = tcA;
        *reinterpret_cast<float4*>(hp + 132 + 8 * g) = tcB;
    }
}

// ---------------- K5: predictor (R2/R4-proven, QPB=16, 256 blocks) -----
__global__ __launch_bounds__(256) void k_predictor(
    const int* __restrict__ s_idx, const int* __restrict__ p_idx,
    const int* __restrict__ n_idx, const int* __restrict__ slot,
    const float* __restrict__ h,
    const float* __restrict__ W_src, const float* __restrict__ b_src,
    const float* __restrict__ W_dst, const float* __restrict__ b_dst,
    const float* __restrict__ W_out, const float* __restrict__ b_out,
    float* __restrict__ out) {
    __shared__ float emb[QPB * 3][DIN];       // 48 KB; row = t*16 + q
    const int tid   = threadIdx.x;
    const int qbase = blockIdx.x * QPB;

    for (int r = tid; r < QPB * 3 * 64; r += 256) {
        int row = r >> 6;                     // 0..47
        int c4  = r & 63;
        int t   = row >> 4;
        int q   = row & 15;
        const int* idxarr = (t == 0) ? s_idx : (t == 1) ? p_idx : n_idx;
        int node = idxarr[qbase + q];
        int sl   = slot[node];
        float4 v = *reinterpret_cast<const float4*>(h + (size_t)sl * DIN + c4 * 4);
        *reinterpret_cast<float4*>(&emb[row][c4 * 4]) = v;
    }
    __syncthreads();

    const int cg  = tid & 31;
    const int j4  = cg << 2;
    const int grp = tid >> 5;
    const int q0  = grp * 2, q1 = grp * 2 + 1;

    float aS[2][4], aP[2][4], aN[2][4];
    #pragma unroll
    for (int c = 0; c < 4; ++c) {
        float bs = b_src[j4 + c], bd = b_dst[j4 + c];
        aS[0][c] = bs; aS[1][c] = bs;
        aP[0][c] = bd; aP[1][c] = bd;
        aN[0][c] = bd; aN[1][c] = bd;
    }

    const float* e_s0 = emb[0 * QPB + q0];
    const float* e_s1 = emb[0 * QPB + q1];
    const float* e_p0 = emb[1 * QPB + q0];
    const float* e_p1 = emb[1 * QPB + q1];
    const float* e_n0 = emb[2 * QPB + q0];
    const float* e_n1 = emb[2 * QPB + q1];
    const float* wsp = W_src + j4;
    const float* wdp = W_dst + j4;

    #pragma unroll 2
    for (int k = 0; k < DIN; k += 4) {
        float4 s0 = *reinterpret_cast<const float4*>(e_s0 + k);
        float4 s1 = *reinterpret_cast<const float4*>(e_s1 + k);
        float4 p0 = *reinterpret_cast<const float4*>(e_p0 + k);
        float4 p1 = *reinterpret_cast<const float4*>(e_p1 + k);
        float4 n0 = *reinterpret_cast<const float4*>(e_n0 + k);
        float4 n1 = *reinterpret_cast<const float4*>(e_n1 + k);
        #pragma unroll
        for (int kk = 0; kk < 4; ++kk) {
            float4 ws = *reinterpret_cast<const float4*>(wsp + (size_t)(k + kk) * HID);
            float4 wd = *reinterpret_cast<const float4*>(wdp + (size_t)(k + kk) * HID);
            float sv0 = (&s0.x)[kk], sv1 = (&s1.x)[kk];
            float pv0 = (&p0.x)[kk], pv1 = (&p1.x)[kk];
            float nv0 = (&n0.x)[kk], nv1 = (&n1.x)[kk];
            #pragma unroll
            for (int c = 0; c < 4; ++c) {
                float wsc = (&ws.x)[c], wdc = (&wd.x)[c];
                aS[0][c] += sv0 * wsc;  aS[1][c] += sv1 * wsc;
                aP[0][c] += pv0 * wdc;  aP[1][c] += pv1 * wdc;
                aN[0][c] += nv0 * wdc;  aN[1][c] += nv1 * wdc;
            }
        }
    }

    float wo[4];
    #pragma unroll
    for (int c = 0; c < 4; ++c) wo[c] = W_out[j4 + c];

    float rP0 = 0.f, rN0 = 0.f, rP1 = 0.f, rN1 = 0.f;
    #pragma unroll
    for (int c = 0; c < 4; ++c) {
        rP0 += fmaxf(aS[0][c] + aP[0][c], 0.f) * wo[c];
        rN0 += fmaxf(aS[0][c] + aN[0][c], 0.f) * wo[c];
        rP1 += fmaxf(aS[1][c] + aP[1][c], 0.f) * wo[c];
        rN1 += fmaxf(aS[1][c] + aN[1][c], 0.f) * wo[c];
    }

    #pragma unroll
    for (int off = 16; off; off >>= 1) {
        rP0 += __shfl_xor(rP0, off);
        rN0 += __shfl_xor(rN0, off);
        rP1 += __shfl_xor(rP1, off);
        rN1 += __shfl_xor(rN1, off);
    }
    if (cg == 0) {
        float bo = b_out[0];
        out[qbase + q0]     = rP0 + bo;
        out[qbase + q1]     = rP1 + bo;
        out[Q + qbase + q0] = rN0 + bo;
        out[Q + qbase + q1] = rN1 + bo;
    }
}

// ---------------- launch ----------------

extern "C" void kernel_launch(void* const* d_in, const int* in_sizes, int n_in,
                              void* d_out, int out_size, void* d_ws, size_t ws_size,
                              hipStream_t stream) {
    const int*   src     = (const int*)d_in[0];
    const int*   dst     = (const int*)d_in[1];
    const float* ef      = (const float*)d_in[2];
    const float* bt      = (const float*)d_in[3];
    const float* node_ts = (const float*)d_in[4];
    const int*   s_idx   = (const int*)d_in[5];
    const int*   p_idx   = (const int*)d_in[6];
    const int*   n_idx   = (const int*)d_in[7];
    const float* time_w  = (const float*)d_in[8];
    const float* time_b  = (const float*)d_in[9];
    const float* W_src   = (const float*)d_in[10];
    const float* b_src   = (const float*)d_in[11];
    const float* W_dst   = (const float*)d_in[12];
    const float* b_dst   = (const float*)d_in[13];
    const float* W_out   = (const float*)d_in[14];
    const float* b_out   = (const float*)d_in[15];
    float*       out     = (float*)d_out;

    // workspace layout (bytes)
    char* ws = (char*)d_ws;
    int*   slot  = (int*)ws;                          // [100000]
    int*   cnt   = (int*)(ws + 512 * 1024);           // [12288]
    int2*  edata = (int2*)(ws + 1024 * 1024);         // [12288*64] int2 = 6.3 MB
    float* h     = (float*)(ws + 8 * 1024 * 1024);    // [12288*256] = 12.6 MB

    k_init<<<(N_NODES / 4 + NSLOT / 4 + 255) / 256, 256, 0, stream>>>(
        (int4*)slot, (int4*)cnt);
    k_claim<<<NSLOT / 256, 256, 0, stream>>>(s_idx, p_idx, n_idx, slot);
    k_build<<<(N_EDGES + 255) / 256, 256, 0, stream>>>(src, dst, bt, node_ts,
                                                       slot, cnt, edata);
    k_aggregate<<<NSLOT / 4, 256, 0, stream>>>(cnt, edata, ef, time_w, time_b, h);
    k_predictor<<<Q / QPB, 256, 0, stream>>>(s_idx, p_idx, n_idx, slot, h,
                                             W_src, b_src, W_dst, b_dst,
                                             W_out, b_out, out);
}